// Round 5
// baseline (42.255 us; speedup 1.0000x reference)
//
#include <hip/hip_runtime.h>
#include <math.h>

#define B_   128
#define A_   5
#define T_   50
#define HG_  19
#define WG_  19
#define NC_  80
#define HW_  361                 // HG_*WG_
#define AHW  (A_*HW_)            // 1805
#define NCELL (B_*A_*HW_)        // 231040
#define CSTRIDE 425              // channels per batch in input
#define EPS_ 1e-7f
#define NW   16                  // waves per block
#define NTHR 1024
#define SUBS 4                   // blocks per batch
#define CPS  452                 // ceil(1805/4) conf cells per sub-block
#define NPART (B_*SUBS)          // 512 partial rows

__device__ __forceinline__ float softplusf(float x) {
    return (x > 0.f) ? (x + log1pf(expf(-x))) : log1pf(expf(x));
}

__constant__ float c_aw[A_] = {0.57273f, 1.87446f, 3.33843f, 7.88282f, 9.77052f};
__constant__ float c_ah[A_] = {0.677385f, 2.06253f, 5.47434f, 3.52778f, 9.16828f};

// ws layout:
//   0      : float part[NPART][8] = {obj, noobj, cls, box, npos, nmask, 0, 0}
//   16384  : unsigned done        (ticket counter, memset to 0 each launch)

// ---------------- K1: fused loss + last-block final reduction -----------------
__global__ __launch_bounds__(NTHR)
void k_batch(const float* __restrict__ inp, const float* __restrict__ tgt,
             float* __restrict__ part, unsigned* __restrict__ done,
             float* __restrict__ out)
{
    const int b    = blockIdx.x >> 2;
    const int sub  = blockIdx.x & 3;
    const int tid  = threadIdx.x;
    const int lane = tid & 63;
    const int wav  = tid >> 6;

    __shared__ unsigned maskbits[57], ignbits[57];   // 1805 bits each
    __shared__ int    skey[T_];                      // cell idx (a*361+ji) or -1
    __shared__ float4 stval[T_];
    __shared__ int    scid[T_];
    __shared__ uint4  sclsb[T_];                     // {w0,w1,w2, owner}
    __shared__ float  sobj[NW], snoo[NW], scls[NW], sbox[NW], spos[NW];
    __shared__ float  sfin[6][NW];
    __shared__ int    snmask;
    __shared__ int    slast;

    if (tid < 57) { maskbits[tid] = 0u; ignbits[tid] = 0u; }
    if (tid == 0) snmask = 0;
    __syncthreads();

    // ---- phase 1: per-target encode (lanes 0..49 of wave 0) ------------------
    if (tid < T_) {
        const float* tp = tgt + (size_t)(b * T_ + tid) * 5;
        float t0 = tp[0], t1 = tp[1], t2 = tp[2], t3 = tp[3], t4 = tp[4];
        bool valid = (t0 + t1 + t2 + t3 + t4) > 0.f;
        float gx = t0 * WG_, gy = t1 * HG_, gw = t2 * WG_, gh = t3 * HG_;
        int gi = (int)gx; gi = min(max(gi, 0), WG_ - 1);
        int gj = (int)gy; gj = min(max(gj, 0), HG_ - 1);
        float area = gw * gh;
        float bestiou = -1.f; int best = 0; unsigned ibits = 0u;
        #pragma unroll
        for (int a = 0; a < A_; a++) {
            float inter = fminf(gw, c_aw[a]) * fminf(gh, c_ah[a]);
            float uni   = area + c_aw[a] * c_ah[a] - inter + 1e-16f;
            float iou   = inter / uni;
            if (iou > bestiou) { bestiou = iou; best = a; }   // first-index tie
            if (valid && iou > 0.5f) ibits |= (1u << a);
        }
        int cid = (int)t4; cid = min(max(cid, 0), NC_ - 1);
        int key = (best * HG_ + gj) * WG_ + gi;
        skey[tid] = valid ? key : -1;
        scid[tid] = cid;
        float4 tv;
        tv.x = gx - (float)gi;
        tv.y = gy - (float)gj;
        tv.z = gw / c_aw[best];
        tv.w = gh / c_ah[best];
        stval[tid] = tv;
        if (valid) {
            atomicOr(&maskbits[key >> 5], 1u << (key & 31));
            #pragma unroll
            for (int a = 0; a < A_; a++)
                if (ibits & (1u << a)) {
                    int c = (a * HG_ + gj) * WG_ + gi;
                    atomicOr(&ignbits[c >> 5], 1u << (c & 31));
                }
        }
    }
    __syncthreads();

    // ---- phase 1.5: owner (= highest-t target of its cell) + class-bit union -
    bool owner = false;
    if (tid < T_) {
        int mykey = skey[tid];
        if (mykey >= 0) {
            owner = true;
            unsigned w0 = 0, w1 = 0, w2 = 0;
            for (int t2 = 0; t2 < T_; t2++) {
                if (skey[t2] == mykey) {
                    if (t2 > tid) owner = false;   // later target owns this cell
                    int c = scid[t2];
                    if (c < 32)      w0 |= 1u << c;
                    else if (c < 64) w1 |= 1u << (c - 32);
                    else             w2 |= 1u << (c - 64);
                }
            }
            sclsb[tid] = make_uint4(w0, w1, w2, owner ? 1u : 0u);
        } else {
            sclsb[tid] = make_uint4(0u, 0u, 0u, 0u);
        }
    }
    if (wav == 0) {
        unsigned long long om = __ballot(owner);
        if (lane == 0 && sub == 0) snmask = __popcll(om);
    }
    __syncthreads();

    // ---- phase 2: conf channel, contiguous 452-cell slice per sub-block ------
    float objv = 0.f, noov = 0.f;
    {
        int c = sub * CPS + tid;
        if (tid < CPS && c < AHW) {
            int a  = c / HW_;
            int ji = c - a * HW_;
            float x = inp[(size_t)(b * CSTRIDE + a * 85 + 4) * HW_ + ji];
            bool mk = (maskbits[c >> 5] >> (c & 31)) & 1;
            bool ig = (ignbits[c >> 5]  >> (c & 31)) & 1;
            float spx = softplusf(x);                 // -log(1 - sigmoid(x))
            objv = mk ? (spx - x) : 1e-12f;
            noov = ig ? 1e-12f : spx;
        }
    }

    // ---- phase 3: owner cells, one per wave (t = 4*wav + sub) ----------------
    float clsv = 0.f, boxv = 0.f, posv = 0.f;
    {
        const int t = 4 * wav + sub;                 // 0..63 covers 0..49
        uint4 cb = (t < T_) ? sclsb[t] : make_uint4(0u, 0u, 0u, 0u);
        if (cb.w) {
            int key = skey[t];
            int a   = key / HW_;
            int ji  = key - a * HW_;
            float4 tb = stval[t];                    // owner == last writer

            const size_t base = (size_t)(b * CSTRIDE + a * 85) * HW_ + ji;
            float xa = inp[base + (size_t)lane * HW_];                            // ch 0..63
            float xb = (lane < 21) ? inp[base + (size_t)(64 + lane) * HW_] : 0.f; // ch 64..84

            float cls = 0.f;
            if (lane >= 5) {
                int c = lane - 5;                    // classes 0..58
                int tt = ((c < 32 ? (cb.x >> c) : (cb.y >> (c - 32))) & 1);
                cls += softplusf(xa) - (float)tt * xa;
            }
            if (lane < 21) {
                int c = 59 + lane;                   // classes 59..79
                int tt = ((c < 64 ? (cb.y >> (c - 32)) : (cb.z >> (c - 64))) & 1);
                cls += softplusf(xb) - (float)tt * xb;
            }
            #pragma unroll
            for (int off = 32; off; off >>= 1) cls += __shfl_xor(cls, off);

            float x0 = __shfl(xa, 0), x1 = __shfl(xa, 1);
            float x2 = __shfl(xa, 2), x3 = __shfl(xa, 3);
            if (lane == 0) {
                clsv = cls;
                float px = 1.f / (1.f + expf(-x0));
                float py = 1.f / (1.f + expf(-x1));
                float pw = expf(x2);
                float ph = expf(x3);
                float b1x1 = px - pw * 0.5f, b1x2 = px + pw * 0.5f;
                float b1y1 = py - ph * 0.5f, b1y2 = py + ph * 0.5f;
                float b2x1 = tb.x - tb.z * 0.5f, b2x2 = tb.x + tb.z * 0.5f;
                float b2y1 = tb.y - tb.w * 0.5f, b2y2 = tb.y + tb.w * 0.5f;
                float iw = fmaxf(fminf(b1x2, b2x2) - fmaxf(b1x1, b2x1), 0.f);
                float ih = fmaxf(fminf(b1y2, b2y2) - fmaxf(b1y1, b2y1), 0.f);
                float inter = iw * ih;
                float uni = pw * ph + tb.z * tb.w - inter + EPS_;
                float iou = inter / uni;
                float cw = fmaxf(b1x2, b2x2) - fminf(b1x1, b2x1);
                float ch = fmaxf(b1y2, b2y2) - fminf(b1y1, b2y1);
                float c2 = cw * cw + ch * ch + EPS_;
                float rho2 = (tb.x - px) * (tb.x - px) + (tb.y - py) * (tb.y - py);
                float dv = atanf(tb.z / (tb.w + EPS_)) - atanf(pw / (ph + EPS_));
                float v = (4.f / (float)(M_PI * M_PI)) * dv * dv;
                float alpha = v / (v - iou + 1.f + EPS_);
                float ciou = iou - (rho2 / c2 + v * alpha);
                if (ciou > 0.f) { boxv = 1.f - ciou; posv = 1.f; }
            }
        }
    }

    // ---- block reduction + partial-row store + ticket ------------------------
    #pragma unroll
    for (int off = 32; off; off >>= 1) {
        objv += __shfl_xor(objv, off);
        noov += __shfl_xor(noov, off);
    }
    if (lane == 0) { sobj[wav] = objv; snoo[wav] = noov;
                     scls[wav] = clsv; sbox[wav] = boxv; spos[wav] = posv; }
    __syncthreads();
    if (tid == 0) {
        float o = 0.f, n = 0.f, c = 0.f, bx = 0.f, p = 0.f;
        #pragma unroll
        for (int w = 0; w < NW; w++) {
            o += sobj[w]; n += snoo[w]; c += scls[w]; bx += sbox[w]; p += spos[w];
        }
        float* pr = part + (size_t)blockIdx.x * 8;
        // agent-scope stores: bypass local L2 so the (possibly remote) reducer
        // never sees stale lines cached from a previous replay
        __hip_atomic_store(&pr[0], o,  __ATOMIC_RELAXED, __HIP_MEMORY_SCOPE_AGENT);
        __hip_atomic_store(&pr[1], n,  __ATOMIC_RELAXED, __HIP_MEMORY_SCOPE_AGENT);
        __hip_atomic_store(&pr[2], c,  __ATOMIC_RELAXED, __HIP_MEMORY_SCOPE_AGENT);
        __hip_atomic_store(&pr[3], bx, __ATOMIC_RELAXED, __HIP_MEMORY_SCOPE_AGENT);
        __hip_atomic_store(&pr[4], p,  __ATOMIC_RELAXED, __HIP_MEMORY_SCOPE_AGENT);
        __hip_atomic_store(&pr[5], (float)snmask, __ATOMIC_RELAXED, __HIP_MEMORY_SCOPE_AGENT);
        __threadfence();
        unsigned old = __hip_atomic_fetch_add(done, 1u, __ATOMIC_ACQ_REL,
                                              __HIP_MEMORY_SCOPE_AGENT);
        slast = (old == NPART - 1) ? 1 : 0;
    }
    __syncthreads();

    // ---- last block: final reduction over all 512 partial rows ---------------
    if (slast) {
        float v0 = 0.f, v1 = 0.f, v2 = 0.f, v3 = 0.f, v4 = 0.f, v5 = 0.f;
        if (tid < NPART) {                           // one row per thread
            const float* pr = part + (size_t)tid * 8;
            v0 = __hip_atomic_load(&pr[0], __ATOMIC_RELAXED, __HIP_MEMORY_SCOPE_AGENT);
            v1 = __hip_atomic_load(&pr[1], __ATOMIC_RELAXED, __HIP_MEMORY_SCOPE_AGENT);
            v2 = __hip_atomic_load(&pr[2], __ATOMIC_RELAXED, __HIP_MEMORY_SCOPE_AGENT);
            v3 = __hip_atomic_load(&pr[3], __ATOMIC_RELAXED, __HIP_MEMORY_SCOPE_AGENT);
            v4 = __hip_atomic_load(&pr[4], __ATOMIC_RELAXED, __HIP_MEMORY_SCOPE_AGENT);
            v5 = __hip_atomic_load(&pr[5], __ATOMIC_RELAXED, __HIP_MEMORY_SCOPE_AGENT);
        }
        #pragma unroll
        for (int off = 32; off; off >>= 1) {
            v0 += __shfl_xor(v0, off); v1 += __shfl_xor(v1, off);
            v2 += __shfl_xor(v2, off); v3 += __shfl_xor(v3, off);
            v4 += __shfl_xor(v4, off); v5 += __shfl_xor(v5, off);
        }
        if (lane == 0) {
            sfin[0][wav] = v0; sfin[1][wav] = v1; sfin[2][wav] = v2;
            sfin[3][wav] = v3; sfin[4][wav] = v4; sfin[5][wav] = v5;
        }
        __syncthreads();
        if (tid == 0) {
            float s[6] = {0.f, 0.f, 0.f, 0.f, 0.f, 0.f};
            #pragma unroll
            for (int w = 0; w < NW; w++)
                #pragma unroll
                for (int j = 0; j < 6; j++) s[j] += sfin[j][w];
            const float N = (float)NCELL;
            float obj_l = 10.f  * s[0] / N;
            float noo_l = 1.f   * s[1] / N;
            float cls_l = 1.f   * s[2] / fmaxf(s[5] * (float)NC_, 1.f);
            float box_l = 0.05f * s[3] / fmaxf(s[4], 1.f);
            out[0] = (box_l + obj_l + noo_l + cls_l) * (float)B_;
        }
    }
}

extern "C" void kernel_launch(void* const* d_in, const int* in_sizes, int n_in,
                              void* d_out, int out_size, void* d_ws, size_t ws_size,
                              hipStream_t stream)
{
    const float* inp = (const float*)d_in[0];   // (128, 425, 19, 19) f32
    const float* tgt = (const float*)d_in[1];   // (128, 50, 5) f32
    float* out = (float*)d_out;

    char* w = (char*)d_ws;
    float*    part = (float*)(w + 0);           // NPART * 8 floats
    unsigned* done = (unsigned*)(w + 16384);    // ticket counter

    hipMemsetAsync(done, 0, sizeof(unsigned), stream);   // capture-legal node
    k_batch<<<NPART, NTHR, 0, stream>>>(inp, tgt, part, done, out);
}

// Round 6
// 36.541 us; speedup vs baseline: 1.1564x; 1.1564x over previous
//
#include <hip/hip_runtime.h>
#include <math.h>

#define B_   128
#define A_   5
#define T_   50
#define HG_  19
#define WG_  19
#define NC_  80
#define HW_  361                 // HG_*WG_
#define AHW  (A_*HW_)            // 1805
#define NCELL (B_*A_*HW_)        // 231040
#define CSTRIDE 425              // channels per batch in input
#define EPS_ 1e-7f
#define NW   16                  // waves per block
#define NTHR 1024
#define SUBS 4                   // blocks per batch
#define CPS  452                 // ceil(1805/4) conf cells per sub-block
#define NPART (B_*SUBS)          // 512 partial rows
#define TAG_ 0x5AFE0001u

__device__ __forceinline__ float softplusf(float x) {
    return (x > 0.f) ? (x + log1pf(expf(-x))) : log1pf(expf(x));
}

__constant__ float c_aw[A_] = {0.57273f, 1.87446f, 3.33843f, 7.88282f, 9.77052f};
__constant__ float c_ah[A_] = {0.677385f, 2.06253f, 5.47434f, 3.52778f, 9.16828f};

// ws layout:
//   0      : float    part[NPART][8] = {obj, noobj, cls, box, npos, nmask, 0, 0}
//   16384  : unsigned flags[NPART]    (TAG when row ready; reducer resets to 0)

// ---------------- K1: fused loss + block-0 final reduction --------------------
__global__ __launch_bounds__(NTHR)
void k_batch(const float* __restrict__ inp, const float* __restrict__ tgt,
             float* __restrict__ part, unsigned* __restrict__ flags,
             float* __restrict__ out)
{
    const int b    = blockIdx.x >> 2;
    const int sub  = blockIdx.x & 3;
    const int tid  = threadIdx.x;
    const int lane = tid & 63;
    const int wav  = tid >> 6;

    __shared__ unsigned maskbits[57], ignbits[57];   // 1805 bits each
    __shared__ int    skey[T_];                      // cell idx (a*361+ji) or -1
    __shared__ float4 stval[T_];
    __shared__ int    scid[T_];
    __shared__ uint4  sclsb[T_];                     // {w0,w1,w2, owner}
    __shared__ float  sobj[NW], snoo[NW], scls[NW], sbox[NW], spos[NW];
    __shared__ float  sfin[6][NW];
    __shared__ int    snmask;

    if (tid < 57) { maskbits[tid] = 0u; ignbits[tid] = 0u; }
    if (tid == 0) snmask = 0;
    __syncthreads();

    // ---- phase 1: per-target encode (lanes 0..49 of wave 0) ------------------
    if (tid < T_) {
        const float* tp = tgt + (size_t)(b * T_ + tid) * 5;
        float t0 = tp[0], t1 = tp[1], t2 = tp[2], t3 = tp[3], t4 = tp[4];
        bool valid = (t0 + t1 + t2 + t3 + t4) > 0.f;
        float gx = t0 * WG_, gy = t1 * HG_, gw = t2 * WG_, gh = t3 * HG_;
        int gi = (int)gx; gi = min(max(gi, 0), WG_ - 1);
        int gj = (int)gy; gj = min(max(gj, 0), HG_ - 1);
        float area = gw * gh;
        float bestiou = -1.f; int best = 0; unsigned ibits = 0u;
        #pragma unroll
        for (int a = 0; a < A_; a++) {
            float inter = fminf(gw, c_aw[a]) * fminf(gh, c_ah[a]);
            float uni   = area + c_aw[a] * c_ah[a] - inter + 1e-16f;
            float iou   = inter / uni;
            if (iou > bestiou) { bestiou = iou; best = a; }   // first-index tie
            if (valid && iou > 0.5f) ibits |= (1u << a);
        }
        int cid = (int)t4; cid = min(max(cid, 0), NC_ - 1);
        int key = (best * HG_ + gj) * WG_ + gi;
        skey[tid] = valid ? key : -1;
        scid[tid] = cid;
        float4 tv;
        tv.x = gx - (float)gi;
        tv.y = gy - (float)gj;
        tv.z = gw / c_aw[best];
        tv.w = gh / c_ah[best];
        stval[tid] = tv;
        if (valid) {
            atomicOr(&maskbits[key >> 5], 1u << (key & 31));
            #pragma unroll
            for (int a = 0; a < A_; a++)
                if (ibits & (1u << a)) {
                    int c = (a * HG_ + gj) * WG_ + gi;
                    atomicOr(&ignbits[c >> 5], 1u << (c & 31));
                }
        }
    }
    __syncthreads();

    // ---- phase 1.5: owner (= highest-t target of its cell) + class-bit union -
    bool owner = false;
    if (tid < T_) {
        int mykey = skey[tid];
        if (mykey >= 0) {
            owner = true;
            unsigned w0 = 0, w1 = 0, w2 = 0;
            for (int t2 = 0; t2 < T_; t2++) {
                if (skey[t2] == mykey) {
                    if (t2 > tid) owner = false;   // later target owns this cell
                    int c = scid[t2];
                    if (c < 32)      w0 |= 1u << c;
                    else if (c < 64) w1 |= 1u << (c - 32);
                    else             w2 |= 1u << (c - 64);
                }
            }
            sclsb[tid] = make_uint4(w0, w1, w2, owner ? 1u : 0u);
        } else {
            sclsb[tid] = make_uint4(0u, 0u, 0u, 0u);
        }
    }
    if (wav == 0) {
        unsigned long long om = __ballot(owner);
        if (lane == 0 && sub == 0) snmask = __popcll(om);
    }
    __syncthreads();

    // ---- phase 2: conf channel, contiguous 452-cell slice per sub-block ------
    float objv = 0.f, noov = 0.f;
    {
        int c = sub * CPS + tid;
        if (tid < CPS && c < AHW) {
            int a  = c / HW_;
            int ji = c - a * HW_;
            float x = inp[(size_t)(b * CSTRIDE + a * 85 + 4) * HW_ + ji];
            bool mk = (maskbits[c >> 5] >> (c & 31)) & 1;
            bool ig = (ignbits[c >> 5]  >> (c & 31)) & 1;
            float spx = softplusf(x);                 // -log(1 - sigmoid(x))
            objv = mk ? (spx - x) : 1e-12f;
            noov = ig ? 1e-12f : spx;
        }
    }

    // ---- phase 3: owner cells, one per wave (t = 4*wav + sub) ----------------
    float clsv = 0.f, boxv = 0.f, posv = 0.f;
    {
        const int t = 4 * wav + sub;                 // 0..63 covers 0..49
        uint4 cb = (t < T_) ? sclsb[t] : make_uint4(0u, 0u, 0u, 0u);
        if (cb.w) {
            int key = skey[t];
            int a   = key / HW_;
            int ji  = key - a * HW_;
            float4 tb = stval[t];                    // owner == last writer

            const size_t base = (size_t)(b * CSTRIDE + a * 85) * HW_ + ji;
            float xa = inp[base + (size_t)lane * HW_];                            // ch 0..63
            float xb = (lane < 21) ? inp[base + (size_t)(64 + lane) * HW_] : 0.f; // ch 64..84

            float cls = 0.f;
            if (lane >= 5) {
                int c = lane - 5;                    // classes 0..58
                int tt = ((c < 32 ? (cb.x >> c) : (cb.y >> (c - 32))) & 1);
                cls += softplusf(xa) - (float)tt * xa;
            }
            if (lane < 21) {
                int c = 59 + lane;                   // classes 59..79
                int tt = ((c < 64 ? (cb.y >> (c - 32)) : (cb.z >> (c - 64))) & 1);
                cls += softplusf(xb) - (float)tt * xb;
            }
            #pragma unroll
            for (int off = 32; off; off >>= 1) cls += __shfl_xor(cls, off);

            float x0 = __shfl(xa, 0), x1 = __shfl(xa, 1);
            float x2 = __shfl(xa, 2), x3 = __shfl(xa, 3);
            if (lane == 0) {
                clsv = cls;
                float px = 1.f / (1.f + expf(-x0));
                float py = 1.f / (1.f + expf(-x1));
                float pw = expf(x2);
                float ph = expf(x3);
                float b1x1 = px - pw * 0.5f, b1x2 = px + pw * 0.5f;
                float b1y1 = py - ph * 0.5f, b1y2 = py + ph * 0.5f;
                float b2x1 = tb.x - tb.z * 0.5f, b2x2 = tb.x + tb.z * 0.5f;
                float b2y1 = tb.y - tb.w * 0.5f, b2y2 = tb.y + tb.w * 0.5f;
                float iw = fmaxf(fminf(b1x2, b2x2) - fmaxf(b1x1, b2x1), 0.f);
                float ih = fmaxf(fminf(b1y2, b2y2) - fmaxf(b1y1, b2y1), 0.f);
                float inter = iw * ih;
                float uni = pw * ph + tb.z * tb.w - inter + EPS_;
                float iou = inter / uni;
                float cw = fmaxf(b1x2, b2x2) - fminf(b1x1, b2x1);
                float ch = fmaxf(b1y2, b2y2) - fminf(b1y1, b2y1);
                float c2 = cw * cw + ch * ch + EPS_;
                float rho2 = (tb.x - px) * (tb.x - px) + (tb.y - py) * (tb.y - py);
                float dv = atanf(tb.z / (tb.w + EPS_)) - atanf(pw / (ph + EPS_));
                float v = (4.f / (float)(M_PI * M_PI)) * dv * dv;
                float alpha = v / (v - iou + 1.f + EPS_);
                float ciou = iou - (rho2 / c2 + v * alpha);
                if (ciou > 0.f) { boxv = 1.f - ciou; posv = 1.f; }
            }
        }
    }

    // ---- block reduction + partial-row store + ready flag --------------------
    #pragma unroll
    for (int off = 32; off; off >>= 1) {
        objv += __shfl_xor(objv, off);
        noov += __shfl_xor(noov, off);
    }
    if (lane == 0) { sobj[wav] = objv; snoo[wav] = noov;
                     scls[wav] = clsv; sbox[wav] = boxv; spos[wav] = posv; }
    __syncthreads();
    if (tid == 0) {
        float o = 0.f, n = 0.f, c = 0.f, bx = 0.f, p = 0.f;
        #pragma unroll
        for (int w = 0; w < NW; w++) {
            o += sobj[w]; n += snoo[w]; c += scls[w]; bx += sbox[w]; p += spos[w];
        }
        float* pr = part + (size_t)blockIdx.x * 8;
        __hip_atomic_store(&pr[0], o,  __ATOMIC_RELAXED, __HIP_MEMORY_SCOPE_AGENT);
        __hip_atomic_store(&pr[1], n,  __ATOMIC_RELAXED, __HIP_MEMORY_SCOPE_AGENT);
        __hip_atomic_store(&pr[2], c,  __ATOMIC_RELAXED, __HIP_MEMORY_SCOPE_AGENT);
        __hip_atomic_store(&pr[3], bx, __ATOMIC_RELAXED, __HIP_MEMORY_SCOPE_AGENT);
        __hip_atomic_store(&pr[4], p,  __ATOMIC_RELAXED, __HIP_MEMORY_SCOPE_AGENT);
        __hip_atomic_store(&pr[5], (float)snmask, __ATOMIC_RELAXED, __HIP_MEMORY_SCOPE_AGENT);
        __threadfence();                              // release partials
        __hip_atomic_store(&flags[blockIdx.x], TAG_, __ATOMIC_RELEASE,
                           __HIP_MEMORY_SCOPE_AGENT);
    }

    // ---- block 0: wait for all rows, reduce, write out, reset flags ----------
    if (blockIdx.x == 0) {
        if (tid < NPART) {
            while (__hip_atomic_load(&flags[tid], __ATOMIC_RELAXED,
                                     __HIP_MEMORY_SCOPE_AGENT) != TAG_) {
                __builtin_amdgcn_s_sleep(1);
            }
        }
        __syncthreads();
        __builtin_amdgcn_fence(__ATOMIC_ACQUIRE, "agent");

        float v0 = 0.f, v1 = 0.f, v2 = 0.f, v3 = 0.f, v4 = 0.f, v5 = 0.f;
        if (tid < NPART) {                           // one row per thread
            const float* pr = part + (size_t)tid * 8;
            v0 = __hip_atomic_load(&pr[0], __ATOMIC_RELAXED, __HIP_MEMORY_SCOPE_AGENT);
            v1 = __hip_atomic_load(&pr[1], __ATOMIC_RELAXED, __HIP_MEMORY_SCOPE_AGENT);
            v2 = __hip_atomic_load(&pr[2], __ATOMIC_RELAXED, __HIP_MEMORY_SCOPE_AGENT);
            v3 = __hip_atomic_load(&pr[3], __ATOMIC_RELAXED, __HIP_MEMORY_SCOPE_AGENT);
            v4 = __hip_atomic_load(&pr[4], __ATOMIC_RELAXED, __HIP_MEMORY_SCOPE_AGENT);
            v5 = __hip_atomic_load(&pr[5], __ATOMIC_RELAXED, __HIP_MEMORY_SCOPE_AGENT);
        }
        #pragma unroll
        for (int off = 32; off; off >>= 1) {
            v0 += __shfl_xor(v0, off); v1 += __shfl_xor(v1, off);
            v2 += __shfl_xor(v2, off); v3 += __shfl_xor(v3, off);
            v4 += __shfl_xor(v4, off); v5 += __shfl_xor(v5, off);
        }
        if (lane == 0) {
            sfin[0][wav] = v0; sfin[1][wav] = v1; sfin[2][wav] = v2;
            sfin[3][wav] = v3; sfin[4][wav] = v4; sfin[5][wav] = v5;
        }
        __syncthreads();
        if (tid == 0) {
            float s[6] = {0.f, 0.f, 0.f, 0.f, 0.f, 0.f};
            #pragma unroll
            for (int w = 0; w < NW; w++)
                #pragma unroll
                for (int j = 0; j < 6; j++) s[j] += sfin[j][w];
            const float N = (float)NCELL;
            float obj_l = 10.f  * s[0] / N;
            float noo_l = 1.f   * s[1] / N;
            float cls_l = 1.f   * s[2] / fmaxf(s[5] * (float)NC_, 1.f);
            float box_l = 0.05f * s[3] / fmaxf(s[4], 1.f);
            out[0] = (box_l + obj_l + noo_l + cls_l) * (float)B_;
        }
        __syncthreads();                              // all reads done
        if (tid < NPART)                              // arm for next replay
            __hip_atomic_store(&flags[tid], 0u, __ATOMIC_RELAXED,
                               __HIP_MEMORY_SCOPE_AGENT);
    }
}

extern "C" void kernel_launch(void* const* d_in, const int* in_sizes, int n_in,
                              void* d_out, int out_size, void* d_ws, size_t ws_size,
                              hipStream_t stream)
{
    const float* inp = (const float*)d_in[0];   // (128, 425, 19, 19) f32
    const float* tgt = (const float*)d_in[1];   // (128, 50, 5) f32
    float* out = (float*)d_out;

    char* w = (char*)d_ws;
    float*    part  = (float*)(w + 0);          // NPART * 8 floats
    unsigned* flags = (unsigned*)(w + 16384);   // NPART ready-flags

    k_batch<<<NPART, NTHR, 0, stream>>>(inp, tgt, part, flags, out);
}

// Round 7
// 32.172 us; speedup vs baseline: 1.3134x; 1.1358x over previous
//
#include <hip/hip_runtime.h>
#include <math.h>

#define B_   128
#define A_   5
#define T_   50
#define HG_  19
#define WG_  19
#define NC_  80
#define HW_  361                 // HG_*WG_
#define AHW  (A_*HW_)            // 1805
#define NCELL (B_*A_*HW_)        // 231040
#define CSTRIDE 425              // channels per batch in input
#define EPS_ 1e-7f
#define NW   16                  // waves per block
#define NTHR 1024
#define SUBS 4                   // blocks per batch
#define CPS  452                 // ceil(1805/4) conf cells per sub-block
#define NPART (B_*SUBS)          // 512 partial rows

__device__ __forceinline__ float softplusf(float x) {
    return (x > 0.f) ? (x + log1pf(expf(-x))) : log1pf(expf(x));
}

__constant__ float c_aw[A_] = {0.57273f, 1.87446f, 3.33843f, 7.88282f, 9.77052f};
__constant__ float c_ah[A_] = {0.677385f, 2.06253f, 5.47434f, 3.52778f, 9.16828f};

// ws layout: float part[NPART][8] = {obj, noobj, cls, box, npos, nmask, 0, 0}

// ---------------- K1: fused per-batch loss, 4 sub-blocks per batch ------------
// Load scheduling: conf-channel load and the wave's own-cell 85-channel gather
// are issued BEFORE the LDS scan phases; registers survive barriers, so the
// scan runs under the memory latency instead of after it.
__global__ __launch_bounds__(NTHR)
void k_batch(const float* __restrict__ inp, const float* __restrict__ tgt,
             float* __restrict__ part)
{
    const int b    = blockIdx.x >> 2;
    const int sub  = blockIdx.x & 3;
    const int tid  = threadIdx.x;
    const int lane = tid & 63;
    const int wav  = tid >> 6;

    __shared__ unsigned maskbits[57], ignbits[57];   // 1805 bits each
    __shared__ int    skey[T_];                      // cell idx (a*361+ji) or -1
    __shared__ int    scid[T_];
    __shared__ uint4  sclsb[T_];                     // {w0,w1,w2, owner}
    __shared__ float  sobj[NW], snoo[NW], scls[NW], sbox[NW], spos[NW];
    __shared__ int    snmask;

    // ---- prefetch 0: conf channel (no dependencies) --------------------------
    const int cc = sub * CPS + tid;
    const bool cvalid = (tid < CPS) && (cc < AHW);
    float xconf = 0.f;
    if (cvalid) {
        int ca  = cc / HW_;
        int cji = cc - ca * HW_;
        xconf = inp[(size_t)(b * CSTRIDE + ca * 85 + 4) * HW_ + cji];
    }

    // ---- prefetch 1: this wave's candidate target, in-register encode --------
    const int t = 4 * wav + sub;                     // wave's owner-candidate
    bool wvalid = false;
    float xa = 0.f, xb = 0.f;
    float4 tb = make_float4(0.f, 0.f, 0.f, 0.f);
    int wa = 0, wji = 0;
    if (t < T_) {
        const float* tp = tgt + (size_t)(b * T_ + t) * 5;   // broadcast load
        float t0 = tp[0], t1 = tp[1], t2 = tp[2], t3 = tp[3], t4 = tp[4];
        wvalid = (t0 + t1 + t2 + t3 + t4) > 0.f;
        float gx = t0 * WG_, gy = t1 * HG_, gw = t2 * WG_, gh = t3 * HG_;
        int gi = (int)gx; gi = min(max(gi, 0), WG_ - 1);
        int gj = (int)gy; gj = min(max(gj, 0), HG_ - 1);
        float area = gw * gh;
        float bestiou = -1.f; int best = 0;
        #pragma unroll
        for (int a = 0; a < A_; a++) {
            float inter = fminf(gw, c_aw[a]) * fminf(gh, c_ah[a]);
            float uni   = area + c_aw[a] * c_ah[a] - inter + 1e-16f;
            float iou   = inter / uni;
            if (iou > bestiou) { bestiou = iou; best = a; }
        }
        int key = (best * HG_ + gj) * WG_ + gi;
        wa  = key / HW_;
        wji = key - wa * HW_;
        tb.x = gx - (float)gi;
        tb.y = gy - (float)gj;
        tb.z = gw / c_aw[best];
        tb.w = gh / c_ah[best];
        if (wvalid) {
            // issue the 85-channel gather NOW; consumed after the scan barrier
            const size_t base = (size_t)(b * CSTRIDE + wa * 85) * HW_ + wji;
            xa = inp[base + (size_t)lane * HW_];                            // ch 0..63
            if (lane < 21) xb = inp[base + (size_t)(64 + lane) * HW_];      // ch 64..84
        }
    }

    // ---- LDS init ------------------------------------------------------------
    if (tid < 57) { maskbits[tid] = 0u; ignbits[tid] = 0u; }
    if (tid == 0) snmask = 0;
    __syncthreads();

    // ---- phase 1: per-target encode into LDS (lanes 0..49 of wave 0) ---------
    if (tid < T_) {
        const float* tp = tgt + (size_t)(b * T_ + tid) * 5;  // L1-warm reload
        float t0 = tp[0], t1 = tp[1], t2 = tp[2], t3 = tp[3], t4 = tp[4];
        bool valid = (t0 + t1 + t2 + t3 + t4) > 0.f;
        float gx = t0 * WG_, gy = t1 * HG_, gw = t2 * WG_, gh = t3 * HG_;
        int gi = (int)gx; gi = min(max(gi, 0), WG_ - 1);
        int gj = (int)gy; gj = min(max(gj, 0), HG_ - 1);
        float area = gw * gh;
        float bestiou = -1.f; int best = 0; unsigned ibits = 0u;
        #pragma unroll
        for (int a = 0; a < A_; a++) {
            float inter = fminf(gw, c_aw[a]) * fminf(gh, c_ah[a]);
            float uni   = area + c_aw[a] * c_ah[a] - inter + 1e-16f;
            float iou   = inter / uni;
            if (iou > bestiou) { bestiou = iou; best = a; }   // first-index tie
            if (valid && iou > 0.5f) ibits |= (1u << a);
        }
        int cid = (int)t4; cid = min(max(cid, 0), NC_ - 1);
        int key = (best * HG_ + gj) * WG_ + gi;
        skey[tid] = valid ? key : -1;
        scid[tid] = cid;
        if (valid) {
            atomicOr(&maskbits[key >> 5], 1u << (key & 31));
            #pragma unroll
            for (int a = 0; a < A_; a++)
                if (ibits & (1u << a)) {
                    int c = (a * HG_ + gj) * WG_ + gi;
                    atomicOr(&ignbits[c >> 5], 1u << (c & 31));
                }
        }
    }
    __syncthreads();

    // ---- phase 1.5: owner (= highest-t target of its cell) + class-bit union -
    bool owner = false;
    if (tid < T_) {
        int mykey = skey[tid];
        if (mykey >= 0) {
            owner = true;
            unsigned w0 = 0, w1 = 0, w2 = 0;
            for (int t2 = 0; t2 < T_; t2++) {
                if (skey[t2] == mykey) {
                    if (t2 > tid) owner = false;   // later target owns this cell
                    int c = scid[t2];
                    if (c < 32)      w0 |= 1u << c;
                    else if (c < 64) w1 |= 1u << (c - 32);
                    else             w2 |= 1u << (c - 64);
                }
            }
            sclsb[tid] = make_uint4(w0, w1, w2, owner ? 1u : 0u);
        } else {
            sclsb[tid] = make_uint4(0u, 0u, 0u, 0u);
        }
    }
    if (wav == 0) {
        unsigned long long om = __ballot(owner);
        if (lane == 0 && sub == 0) snmask = __popcll(om);
    }
    __syncthreads();

    // ---- phase 2: conf loss from prefetched xconf ----------------------------
    float objv = 0.f, noov = 0.f;
    if (cvalid) {
        bool mk = (maskbits[cc >> 5] >> (cc & 31)) & 1;
        bool ig = (ignbits[cc >> 5]  >> (cc & 31)) & 1;
        float spx = softplusf(xconf);             // -log(1 - sigmoid(x))
        objv = mk ? (spx - xconf) : 1e-12f;
        noov = ig ? 1e-12f : spx;
    }

    // ---- phase 3: consume gather if this wave's target owns its cell ---------
    float clsv = 0.f, boxv = 0.f, posv = 0.f;
    {
        uint4 cb = (t < T_) ? sclsb[t] : make_uint4(0u, 0u, 0u, 0u);
        if (cb.w) {                                // owner (implies wvalid)
            float cls = 0.f;
            if (lane >= 5) {
                int c = lane - 5;                  // classes 0..58
                int tt = ((c < 32 ? (cb.x >> c) : (cb.y >> (c - 32))) & 1);
                cls += softplusf(xa) - (float)tt * xa;
            }
            if (lane < 21) {
                int c = 59 + lane;                 // classes 59..79
                int tt = ((c < 64 ? (cb.y >> (c - 32)) : (cb.z >> (c - 64))) & 1);
                cls += softplusf(xb) - (float)tt * xb;
            }
            #pragma unroll
            for (int off = 32; off; off >>= 1) cls += __shfl_xor(cls, off);

            float x0 = __shfl(xa, 0), x1 = __shfl(xa, 1);
            float x2 = __shfl(xa, 2), x3 = __shfl(xa, 3);
            if (lane == 0) {
                clsv = cls;
                float px = 1.f / (1.f + expf(-x0));
                float py = 1.f / (1.f + expf(-x1));
                float pw = expf(x2);
                float ph = expf(x3);
                float b1x1 = px - pw * 0.5f, b1x2 = px + pw * 0.5f;
                float b1y1 = py - ph * 0.5f, b1y2 = py + ph * 0.5f;
                float b2x1 = tb.x - tb.z * 0.5f, b2x2 = tb.x + tb.z * 0.5f;
                float b2y1 = tb.y - tb.w * 0.5f, b2y2 = tb.y + tb.w * 0.5f;
                float iw = fmaxf(fminf(b1x2, b2x2) - fmaxf(b1x1, b2x1), 0.f);
                float ih = fmaxf(fminf(b1y2, b2y2) - fmaxf(b1y1, b2y1), 0.f);
                float inter = iw * ih;
                float uni = pw * ph + tb.z * tb.w - inter + EPS_;
                float iou = inter / uni;
                float cw = fmaxf(b1x2, b2x2) - fminf(b1x1, b2x1);
                float ch = fmaxf(b1y2, b2y2) - fminf(b1y1, b2y1);
                float c2 = cw * cw + ch * ch + EPS_;
                float rho2 = (tb.x - px) * (tb.x - px) + (tb.y - py) * (tb.y - py);
                float dv = atanf(tb.z / (tb.w + EPS_)) - atanf(pw / (ph + EPS_));
                float v = (4.f / (float)(M_PI * M_PI)) * dv * dv;
                float alpha = v / (v - iou + 1.f + EPS_);
                float ciou = iou - (rho2 / c2 + v * alpha);
                if (ciou > 0.f) { boxv = 1.f - ciou; posv = 1.f; }
            }
        }
    }

    // ---- block reduction -----------------------------------------------------
    #pragma unroll
    for (int off = 32; off; off >>= 1) {
        objv += __shfl_xor(objv, off);
        noov += __shfl_xor(noov, off);
    }
    if (lane == 0) { sobj[wav] = objv; snoo[wav] = noov;
                     scls[wav] = clsv; sbox[wav] = boxv; spos[wav] = posv; }
    __syncthreads();
    if (tid == 0) {
        float o = 0.f, n = 0.f, c = 0.f, bx = 0.f, p = 0.f;
        #pragma unroll
        for (int w = 0; w < NW; w++) {
            o += sobj[w]; n += snoo[w]; c += scls[w]; bx += sbox[w]; p += spos[w];
        }
        float* pr = part + (size_t)blockIdx.x * 8;
        pr[0] = o; pr[1] = n; pr[2] = c; pr[3] = bx;
        pr[4] = p; pr[5] = (float)snmask; pr[6] = 0.f; pr[7] = 0.f;
    }
}

// ---------------- K2: final reduction over 512 partials ------------------------
__global__ __launch_bounds__(512)
void k_final(const float* __restrict__ part, float* __restrict__ out)
{
    const int tid  = threadIdx.x;
    const int lane = tid & 63;
    const int wav  = tid >> 6;
    __shared__ float sfin[6][8];

    const float* pr = part + (size_t)tid * 8;       // one row per thread
    float v0 = pr[0], v1 = pr[1], v2 = pr[2], v3 = pr[3], v4 = pr[4], v5 = pr[5];
    #pragma unroll
    for (int off = 32; off; off >>= 1) {
        v0 += __shfl_xor(v0, off); v1 += __shfl_xor(v1, off);
        v2 += __shfl_xor(v2, off); v3 += __shfl_xor(v3, off);
        v4 += __shfl_xor(v4, off); v5 += __shfl_xor(v5, off);
    }
    if (lane == 0) {
        sfin[0][wav] = v0; sfin[1][wav] = v1; sfin[2][wav] = v2;
        sfin[3][wav] = v3; sfin[4][wav] = v4; sfin[5][wav] = v5;
    }
    __syncthreads();
    if (tid == 0) {
        float s[6] = {0.f, 0.f, 0.f, 0.f, 0.f, 0.f};
        #pragma unroll
        for (int w = 0; w < 8; w++)
            #pragma unroll
            for (int j = 0; j < 6; j++) s[j] += sfin[j][w];
        const float N = (float)NCELL;
        float obj_l = 10.f  * s[0] / N;
        float noo_l = 1.f   * s[1] / N;
        float cls_l = 1.f   * s[2] / fmaxf(s[5] * (float)NC_, 1.f);
        float box_l = 0.05f * s[3] / fmaxf(s[4], 1.f);
        out[0] = (box_l + obj_l + noo_l + cls_l) * (float)B_;
    }
}

extern "C" void kernel_launch(void* const* d_in, const int* in_sizes, int n_in,
                              void* d_out, int out_size, void* d_ws, size_t ws_size,
                              hipStream_t stream)
{
    const float* inp = (const float*)d_in[0];   // (128, 425, 19, 19) f32
    const float* tgt = (const float*)d_in[1];   // (128, 50, 5) f32
    float* out = (float*)d_out;
    float* part = (float*)d_ws;                 // NPART * 8 floats

    k_batch<<<NPART, NTHR, 0, stream>>>(inp, tgt, part);
    k_final<<<1, 512, 0, stream>>>(part, out);
}

// Round 8
// 27.730 us; speedup vs baseline: 1.5238x; 1.1602x over previous
//
#include <hip/hip_runtime.h>
#include <math.h>

#define B_   128
#define A_   5
#define T_   50
#define HG_  19
#define WG_  19
#define NC_  80
#define HW_  361                 // HG_*WG_
#define AHW  (A_*HW_)            // 1805
#define NCELL (B_*A_*HW_)        // 231040
#define CSTRIDE 425              // channels per batch in input
#define EPS_ 1e-7f
#define NW   8                   // waves per block
#define NTHR 512
#define SUBS 8                   // blocks per batch
#define CPS  226                 // ceil(1805/8) conf cells per sub-block
#define NPART (B_*SUBS)          // 1024 partial rows

__device__ __forceinline__ float softplusf(float x) {
    return (x > 0.f) ? (x + log1pf(expf(-x))) : log1pf(expf(x));
}

__constant__ float c_aw[A_] = {0.57273f, 1.87446f, 3.33843f, 7.88282f, 9.77052f};
__constant__ float c_ah[A_] = {0.677385f, 2.06253f, 5.47434f, 3.52778f, 9.16828f};

// ws layout: float part[NPART][8] = {obj, noobj, cls, box, npos, nmask, 0, 0}

// ---------------- K1: fused per-batch loss, 8 sub-blocks per batch ------------
// block=512: __launch_bounds__(512,8) pins 8 waves/EU = 4 blocks/CU, so all
// 1024 blocks are co-resident in a single dispatch round.
__global__ __launch_bounds__(NTHR, 8)
void k_batch(const float* __restrict__ inp, const float* __restrict__ tgt,
             float* __restrict__ part)
{
    const int b    = blockIdx.x >> 3;
    const int sub  = blockIdx.x & 7;
    const int tid  = threadIdx.x;
    const int lane = tid & 63;
    const int wav  = tid >> 6;

    __shared__ unsigned maskbits[57], ignbits[57];   // 1805 bits each
    __shared__ int    skey[T_];                      // cell idx (a*361+ji) or -1
    __shared__ float4 stval[T_];
    __shared__ int    scid[T_];
    __shared__ uint4  sclsb[T_];                     // {w0,w1,w2, owner}
    __shared__ float  sobj[NW], snoo[NW], scls[NW], sbox[NW], spos[NW];
    __shared__ int    snmask;

    if (tid < 57) { maskbits[tid] = 0u; ignbits[tid] = 0u; }
    if (tid == 0) snmask = 0;
    __syncthreads();

    // ---- phase 1: per-target encode (lanes 0..49 of wave 0) ------------------
    if (tid < T_) {
        const float* tp = tgt + (size_t)(b * T_ + tid) * 5;
        float t0 = tp[0], t1 = tp[1], t2 = tp[2], t3 = tp[3], t4 = tp[4];
        bool valid = (t0 + t1 + t2 + t3 + t4) > 0.f;
        float gx = t0 * WG_, gy = t1 * HG_, gw = t2 * WG_, gh = t3 * HG_;
        int gi = (int)gx; gi = min(max(gi, 0), WG_ - 1);
        int gj = (int)gy; gj = min(max(gj, 0), HG_ - 1);
        float area = gw * gh;
        float bestiou = -1.f; int best = 0; unsigned ibits = 0u;
        #pragma unroll
        for (int a = 0; a < A_; a++) {
            float inter = fminf(gw, c_aw[a]) * fminf(gh, c_ah[a]);
            float uni   = area + c_aw[a] * c_ah[a] - inter + 1e-16f;
            float iou   = inter / uni;
            if (iou > bestiou) { bestiou = iou; best = a; }   // first-index tie
            if (valid && iou > 0.5f) ibits |= (1u << a);
        }
        int cid = (int)t4; cid = min(max(cid, 0), NC_ - 1);
        int key = (best * HG_ + gj) * WG_ + gi;
        skey[tid] = valid ? key : -1;
        scid[tid] = cid;
        float4 tv;
        tv.x = gx - (float)gi;
        tv.y = gy - (float)gj;
        tv.z = gw / c_aw[best];
        tv.w = gh / c_ah[best];
        stval[tid] = tv;
        if (valid) {
            atomicOr(&maskbits[key >> 5], 1u << (key & 31));
            #pragma unroll
            for (int a = 0; a < A_; a++)
                if (ibits & (1u << a)) {
                    int c = (a * HG_ + gj) * WG_ + gi;
                    atomicOr(&ignbits[c >> 5], 1u << (c & 31));
                }
        }
    }
    __syncthreads();

    // ---- phase 1.5: owner (= highest-t target of its cell) + class-bit union -
    bool owner = false;
    if (tid < T_) {
        int mykey = skey[tid];
        if (mykey >= 0) {
            owner = true;
            unsigned w0 = 0, w1 = 0, w2 = 0;
            for (int t2 = 0; t2 < T_; t2++) {
                if (skey[t2] == mykey) {
                    if (t2 > tid) owner = false;   // later target owns this cell
                    int c = scid[t2];
                    if (c < 32)      w0 |= 1u << c;
                    else if (c < 64) w1 |= 1u << (c - 32);
                    else             w2 |= 1u << (c - 64);
                }
            }
            sclsb[tid] = make_uint4(w0, w1, w2, owner ? 1u : 0u);
        } else {
            sclsb[tid] = make_uint4(0u, 0u, 0u, 0u);
        }
    }
    if (wav == 0) {
        unsigned long long om = __ballot(owner);
        if (lane == 0 && sub == 0) snmask = __popcll(om);
    }
    __syncthreads();

    // ---- phase 2: conf channel, contiguous 226-cell slice per sub-block ------
    float objv = 0.f, noov = 0.f;
    {
        int c = sub * CPS + tid;
        if (tid < CPS && c < AHW) {
            int a  = c / HW_;
            int ji = c - a * HW_;
            float x = inp[(size_t)(b * CSTRIDE + a * 85 + 4) * HW_ + ji];
            bool mk = (maskbits[c >> 5] >> (c & 31)) & 1;
            bool ig = (ignbits[c >> 5]  >> (c & 31)) & 1;
            float spx = softplusf(x);                 // -log(1 - sigmoid(x))
            objv = mk ? (spx - x) : 1e-12f;
            noov = ig ? 1e-12f : spx;
        }
    }

    // ---- phase 3: owner cells, one per wave (t = 8*wav + sub) ----------------
    float clsv = 0.f, boxv = 0.f, posv = 0.f;
    {
        const int t = 8 * wav + sub;                 // 0..63 covers 0..49
        uint4 cb = (t < T_) ? sclsb[t] : make_uint4(0u, 0u, 0u, 0u);
        if (cb.w) {
            int key = skey[t];
            int a   = key / HW_;
            int ji  = key - a * HW_;
            float4 tb = stval[t];                    // owner == last writer

            const size_t base = (size_t)(b * CSTRIDE + a * 85) * HW_ + ji;
            float xa = inp[base + (size_t)lane * HW_];                            // ch 0..63
            float xb = (lane < 21) ? inp[base + (size_t)(64 + lane) * HW_] : 0.f; // ch 64..84

            float cls = 0.f;
            if (lane >= 5) {
                int c = lane - 5;                    // classes 0..58
                int tt = ((c < 32 ? (cb.x >> c) : (cb.y >> (c - 32))) & 1);
                cls += softplusf(xa) - (float)tt * xa;
            }
            if (lane < 21) {
                int c = 59 + lane;                   // classes 59..79
                int tt = ((c < 64 ? (cb.y >> (c - 32)) : (cb.z >> (c - 64))) & 1);
                cls += softplusf(xb) - (float)tt * xb;
            }
            #pragma unroll
            for (int off = 32; off; off >>= 1) cls += __shfl_xor(cls, off);

            float x0 = __shfl(xa, 0), x1 = __shfl(xa, 1);
            float x2 = __shfl(xa, 2), x3 = __shfl(xa, 3);
            if (lane == 0) {
                clsv = cls;
                float px = 1.f / (1.f + expf(-x0));
                float py = 1.f / (1.f + expf(-x1));
                float pw = expf(x2);
                float ph = expf(x3);
                float b1x1 = px - pw * 0.5f, b1x2 = px + pw * 0.5f;
                float b1y1 = py - ph * 0.5f, b1y2 = py + ph * 0.5f;
                float b2x1 = tb.x - tb.z * 0.5f, b2x2 = tb.x + tb.z * 0.5f;
                float b2y1 = tb.y - tb.w * 0.5f, b2y2 = tb.y + tb.w * 0.5f;
                float iw = fmaxf(fminf(b1x2, b2x2) - fmaxf(b1x1, b2x1), 0.f);
                float ih = fmaxf(fminf(b1y2, b2y2) - fmaxf(b1y1, b2y1), 0.f);
                float inter = iw * ih;
                float uni = pw * ph + tb.z * tb.w - inter + EPS_;
                float iou = inter / uni;
                float cw = fmaxf(b1x2, b2x2) - fminf(b1x1, b2x1);
                float ch = fmaxf(b1y2, b2y2) - fminf(b1y1, b2y1);
                float c2 = cw * cw + ch * ch + EPS_;
                float rho2 = (tb.x - px) * (tb.x - px) + (tb.y - py) * (tb.y - py);
                float dv = atanf(tb.z / (tb.w + EPS_)) - atanf(pw / (ph + EPS_));
                float v = (4.f / (float)(M_PI * M_PI)) * dv * dv;
                float alpha = v / (v - iou + 1.f + EPS_);
                float ciou = iou - (rho2 / c2 + v * alpha);
                if (ciou > 0.f) { boxv = 1.f - ciou; posv = 1.f; }
            }
        }
    }

    // ---- block reduction -----------------------------------------------------
    #pragma unroll
    for (int off = 32; off; off >>= 1) {
        objv += __shfl_xor(objv, off);
        noov += __shfl_xor(noov, off);
    }
    if (lane == 0) { sobj[wav] = objv; snoo[wav] = noov;
                     scls[wav] = clsv; sbox[wav] = boxv; spos[wav] = posv; }
    __syncthreads();
    if (tid == 0) {
        float o = 0.f, n = 0.f, c = 0.f, bx = 0.f, p = 0.f;
        #pragma unroll
        for (int w = 0; w < NW; w++) {
            o += sobj[w]; n += snoo[w]; c += scls[w]; bx += sbox[w]; p += spos[w];
        }
        float* pr = part + (size_t)blockIdx.x * 8;
        pr[0] = o; pr[1] = n; pr[2] = c; pr[3] = bx;
        pr[4] = p; pr[5] = (float)snmask; pr[6] = 0.f; pr[7] = 0.f;
    }
}

// ---------------- K2: final reduction over 1024 partials -----------------------
__global__ __launch_bounds__(512)
void k_final(const float* __restrict__ part, float* __restrict__ out)
{
    const int tid  = threadIdx.x;
    const int lane = tid & 63;
    const int wav  = tid >> 6;
    __shared__ float sfin[6][8];

    const float* p0 = part + (size_t)tid * 8;             // rows tid, tid+512
    const float* p1 = part + (size_t)(tid + 512) * 8;
    float v0 = p0[0] + p1[0], v1 = p0[1] + p1[1], v2 = p0[2] + p1[2];
    float v3 = p0[3] + p1[3], v4 = p0[4] + p1[4], v5 = p0[5] + p1[5];
    #pragma unroll
    for (int off = 32; off; off >>= 1) {
        v0 += __shfl_xor(v0, off); v1 += __shfl_xor(v1, off);
        v2 += __shfl_xor(v2, off); v3 += __shfl_xor(v3, off);
        v4 += __shfl_xor(v4, off); v5 += __shfl_xor(v5, off);
    }
    if (lane == 0) {
        sfin[0][wav] = v0; sfin[1][wav] = v1; sfin[2][wav] = v2;
        sfin[3][wav] = v3; sfin[4][wav] = v4; sfin[5][wav] = v5;
    }
    __syncthreads();
    if (tid == 0) {
        float s[6] = {0.f, 0.f, 0.f, 0.f, 0.f, 0.f};
        #pragma unroll
        for (int w = 0; w < 8; w++)
            #pragma unroll
            for (int j = 0; j < 6; j++) s[j] += sfin[j][w];
        const float N = (float)NCELL;
        float obj_l = 10.f  * s[0] / N;
        float noo_l = 1.f   * s[1] / N;
        float cls_l = 1.f   * s[2] / fmaxf(s[5] * (float)NC_, 1.f);
        float box_l = 0.05f * s[3] / fmaxf(s[4], 1.f);
        out[0] = (box_l + obj_l + noo_l + cls_l) * (float)B_;
    }
}

extern "C" void kernel_launch(void* const* d_in, const int* in_sizes, int n_in,
                              void* d_out, int out_size, void* d_ws, size_t ws_size,
                              hipStream_t stream)
{
    const float* inp = (const float*)d_in[0];   // (128, 425, 19, 19) f32
    const float* tgt = (const float*)d_in[1];   // (128, 50, 5) f32
    float* out = (float*)d_out;
    float* part = (float*)d_ws;                 // NPART * 8 floats

    k_batch<<<B_ * SUBS, NTHR, 0, stream>>>(inp, tgt, part);
    k_final<<<1, 512, 0, stream>>>(part, out);
}